// Round 1
// 1547.060 us; speedup vs baseline: 1.0580x; 1.0580x over previous
//
#include <hip/hip_runtime.h>

typedef __attribute__((ext_vector_type(4))) float f32x4;
typedef __attribute__((ext_vector_type(8))) short short8;
typedef unsigned short bfu16;

typedef const __attribute__((address_space(1))) void* as1cv;
typedef __attribute__((address_space(3))) void* as3v;
#define GLL16(gp, lp) __builtin_amdgcn_global_load_lds((as1cv)(const void*)(gp), (as3v)(void*)(lp), 16, 0, 0)

__device__ __forceinline__ bfu16 f2b(float f) {
    union { float f; unsigned u; } x; x.f = f;
    unsigned r = x.u + 0x7fffu + ((x.u >> 16) & 1u);
    return (bfu16)(r >> 16);
}

// fast erf-based gelu: Abramowitz-Stegun 7.1.26, |err(erf)| <= 1.5e-7, single path (no divergence)
__device__ __forceinline__ float fast_gelu(float v) {
    float z = v * 0.70710678118654752f;
    float a = fabsf(z);
    float t = __builtin_amdgcn_rcpf(fmaf(0.3275911f, a, 1.0f));
    float poly = t * fmaf(t, fmaf(t, fmaf(t, fmaf(t, 1.061405429f, -1.453152027f), 1.421413741f), -0.284496736f), 0.254829592f);
    float e = __expf(-a * a);
    float erfa = fmaf(-poly, e, 1.0f);       // erf(|z|), >= 0
    float erfz = copysignf(erfa, z);
    return 0.5f * v * (1.0f + erfz);
}

// row-swizzle for 128B-stride LDS rows (8 x 16B chunks): chunk ^= ((row ^ (row>>3)) & 7)
#define VSWZ(d) ((((d) ^ ((d) >> 3)) & 7))

// ---------------- weight convert + transpose: W[K][N] fp32 -> Wt[N][K] bf16 ----------------
__global__ __launch_bounds__(256) void k_convw(const float* __restrict__ W, bfu16* __restrict__ Wt,
                                               int K, int N) {
    int idx = blockIdx.x * 256 + threadIdx.x;
    if (idx >= K * N) return;
    int k = idx / N, n = idx - k * N;
    Wt[(size_t)n * K + k] = f2b(W[idx]);
}

// ---------------- LayerNorm over C=384, one wave per row, bf16 out ----------------
__global__ __launch_bounds__(256) void k_ln(const float* __restrict__ x, const float* __restrict__ g,
                                            const float* __restrict__ b, bfu16* __restrict__ y) {
    int wid = threadIdx.x >> 6, lane = threadIdx.x & 63;
    size_t row = (size_t)blockIdx.x * 4 + wid;
    const float* xr = x + row * 384;
    float v[6];
#pragma unroll
    for (int i = 0; i < 6; ++i) v[i] = xr[lane + i * 64];
    float s = 0.f;
#pragma unroll
    for (int i = 0; i < 6; ++i) s += v[i];
#pragma unroll
    for (int off = 1; off < 64; off <<= 1) s += __shfl_xor(s, off, 64);
    float mean = s * (1.0f / 384.0f);
    float q = 0.f;
#pragma unroll
    for (int i = 0; i < 6; ++i) { float d = v[i] - mean; q += d * d; }
#pragma unroll
    for (int off = 1; off < 64; off <<= 1) q += __shfl_xor(q, off, 64);
    float inv = rsqrtf(q * (1.0f / 384.0f) + 1e-5f);
    bfu16* yr = y + row * 384;
#pragma unroll
    for (int i = 0; i < 6; ++i) {
        int c = lane + i * 64;
        yr[c] = f2b((v[i] - mean) * inv * g[c] + b[c]);
    }
}

// ---------------- GEMM: C[M][N] = A[M][K](bf16) @ Bt[N][K]^T(bf16) + bias, fused epilogue ----
// EPI 0: out bf16         1: out fp32 = acc+bias+res (res stride == N)     2: out bf16 = gelu(acc+bias)
// LDS tiles are [128][32] bf16 (64B rows = 4 x 16B chunks). To kill the 8-way ds_read bank
// conflict we XOR-swizzle the chunk with row bits 1-2. global_load_lds writes linearly
// (wave base + lane*16B), so the swizzle is applied by permuting the per-lane GLOBAL source
// chunk (guideline 21: both-sides-or-neither), and the matching XOR on the ds_read offset.
template <int EPI>
__global__ __launch_bounds__(256) void k_gemm(const bfu16* __restrict__ A, const bfu16* __restrict__ Bt,
                                              const float* __restrict__ bias, const float* __restrict__ res,
                                              float* __restrict__ outf, bfu16* __restrict__ outb,
                                              int N, int K) {
    __shared__ __align__(16) bfu16 As[128 * 32];
    __shared__ __align__(16) bfu16 Bs[128 * 32];
    const int tid = threadIdx.x, wid = tid >> 6, lane = tid & 63;
    const int quad = lane >> 4, l16 = lane & 15;
    const int m0 = blockIdx.y * 128, n0 = blockIdx.x * 128;
    const int wm = (wid >> 1) * 64, wn = (wid & 1) * 64;
    // staging: lane l stages (local row l>>2, k-chunk (l&3)^((l>>3)&3)) -> LDS is chunk-swizzled
    const int srow = lane >> 2;
    const int skc = (lane & 3) ^ ((lane >> 3) & 3);
    const bfu16* Ag = A + (size_t)(m0 + wid * 32 + srow) * K + skc * 8;
    const bfu16* Bg = Bt + (size_t)(n0 + wid * 32 + srow) * K + skc * 8;
    bfu16* Al0 = As + (wid * 32) * 32;
    bfu16* Al1 = As + (wid * 32 + 16) * 32;
    bfu16* Bl0 = Bs + (wid * 32) * 32;
    bfu16* Bl1 = Bs + (wid * 32 + 16) * 32;

    // read-side swizzled chunk offset (constant per lane: row bits 1-2 == l16 bits 1-2)
    const int swq = (quad ^ ((l16 >> 1) & 3)) * 8;

    const f32x4 zero = {0.f, 0.f, 0.f, 0.f};
    f32x4 acc[4][4];
#pragma unroll
    for (int i = 0; i < 4; ++i)
#pragma unroll
        for (int j = 0; j < 4; ++j) acc[i][j] = zero;

    for (int k0 = 0; k0 < K; k0 += 32) {
        GLL16(Ag + k0, Al0);
        GLL16(Ag + k0 + 16 * K, Al1);
        GLL16(Bg + k0, Bl0);
        GLL16(Bg + k0 + 16 * K, Bl1);
        __syncthreads();
        short8 af[4], bfr[4];
#pragma unroll
        for (int t = 0; t < 4; ++t) af[t]  = *(const short8*)(As + (wm + t * 16 + l16) * 32 + swq);
#pragma unroll
        for (int t = 0; t < 4; ++t) bfr[t] = *(const short8*)(Bs + (wn + t * 16 + l16) * 32 + swq);
#pragma unroll
        for (int mt = 0; mt < 4; ++mt)
#pragma unroll
            for (int nt = 0; nt < 4; ++nt)
                acc[mt][nt] = __builtin_amdgcn_mfma_f32_16x16x32_bf16(af[mt], bfr[nt], acc[mt][nt], 0, 0, 0);
        __syncthreads();
    }

    // hoist the 4 distinct bias values out of the 64-iteration store loop
    float bv[4];
#pragma unroll
    for (int nt = 0; nt < 4; ++nt) bv[nt] = bias[n0 + wn + nt * 16 + l16];

#pragma unroll
    for (int mt = 0; mt < 4; ++mt)
#pragma unroll
        for (int nt = 0; nt < 4; ++nt)
#pragma unroll
            for (int r = 0; r < 4; ++r) {
                int m = m0 + wm + mt * 16 + quad * 4 + r;
                int n = n0 + wn + nt * 16 + l16;
                float v = acc[mt][nt][r] + bv[nt];
                size_t off = (size_t)m * N + n;
                if (EPI == 0) {
                    outb[off] = f2b(v);
                } else if (EPI == 1) {
                    outf[off] = v + res[off];
                } else {
                    outb[off] = f2b(fast_gelu(v));
                }
            }
}

// ---------------- windowed attention: one wave per (window, head) ----------------
// qkv: [131072][1152] bf16 (natural row order); o: [131072][384] bf16 (natural row order)
// P_s / Vt_s rows are 128B (bank-aligned stride) -> 16-way read conflicts unswizzled;
// chunk-XOR with VSWZ(row) spreads the 8 chunk-spans -> 2 lanes/bank (free).
__global__ __launch_bounds__(256) void k_attn(const bfu16* __restrict__ qkv, const float* __restrict__ rpb,
                                              bfu16* __restrict__ o) {
    __shared__ __align__(16) bfu16 P_s[4][64 * 64];
    __shared__ __align__(16) bfu16 Vt_s[4][32 * 64];
    const int wid = threadIdx.x >> 6, lane = threadIdx.x & 63;
    const int quad = lane >> 4, l16 = lane & 15;
    const int gid = blockIdx.x * 4 + wid;          // 0..24575
    const int win = gid / 12, head = gid - win * 12;
    const int b = win >> 6, wi = (win >> 3) & 7, wj = win & 7;
    const int rowbase = b * 4096 + wi * 8 * 64 + wj * 8;
#define ROWOF(t) (rowbase + ((t) >> 3) * 64 + ((t) & 7))

    // stage V transposed (swizzled): Vt[d][j], lane owns token j=lane
    {
        const bfu16* vr = qkv + (size_t)ROWOF(lane) * 1152 + 768 + head * 32;
        short8 v0 = *(const short8*)(vr);
        short8 v1 = *(const short8*)(vr + 8);
        short8 v2 = *(const short8*)(vr + 16);
        short8 v3 = *(const short8*)(vr + 24);
        bfu16* vt = &Vt_s[wid][0];
        const int lh = lane >> 3, ll = lane & 7;
#pragma unroll
        for (int j = 0; j < 8; ++j) {
            vt[(0  + j) * 64 + ((lh ^ VSWZ(0  + j)) * 8) + ll] = (bfu16)v0[j];
            vt[(8  + j) * 64 + ((lh ^ VSWZ(8  + j)) * 8) + ll] = (bfu16)v1[j];
            vt[(16 + j) * 64 + ((lh ^ VSWZ(16 + j)) * 8) + ll] = (bfu16)v2[j];
            vt[(24 + j) * 64 + ((lh ^ VSWZ(24 + j)) * 8) + ll] = (bfu16)v3[j];
        }
    }

    // Q/K fragments straight from global (both K-major): A[m=lane&15][k=quad*8+j]
    short8 qf[4], kf[4];
#pragma unroll
    for (int t = 0; t < 4; ++t) {
        const size_t r = (size_t)ROWOF(t * 16 + l16) * 1152;
        qf[t] = *(const short8*)(qkv + r + head * 32 + quad * 8);
        kf[t] = *(const short8*)(qkv + r + 384 + head * 32 + quad * 8);
    }
    const f32x4 zero = {0.f, 0.f, 0.f, 0.f};
    f32x4 s[4][4];
#pragma unroll
    for (int ti = 0; ti < 4; ++ti)
#pragma unroll
        for (int tj = 0; tj < 4; ++tj)
            s[ti][tj] = __builtin_amdgcn_mfma_f32_16x16x32_bf16(qf[ti], kf[tj], zero, 0, 0, 0);

    // softmax over j (rows i = ti*16 + quad*4 + r live in 16-lane groups)
    const float scale = 0.17677669529663689f;  // 1/sqrt(32)
    float inv_l[4][4];
#pragma unroll
    for (int ti = 0; ti < 4; ++ti)
#pragma unroll
        for (int r = 0; r < 4; ++r) {
            int i = ti * 16 + quad * 4 + r;
            int yi = i >> 3, xi = i & 7;
            float mv = -1e30f;
#pragma unroll
            for (int tj = 0; tj < 4; ++tj) {
                int j = tj * 16 + l16;
                int idx = (yi - (j >> 3) + 7) * 15 + (xi - (j & 7) + 7);
                float sv = s[ti][tj][r] * scale + rpb[idx * 12 + head];
                s[ti][tj][r] = sv;
                mv = fmaxf(mv, sv);
            }
#pragma unroll
            for (int off = 1; off < 16; off <<= 1) mv = fmaxf(mv, __shfl_xor(mv, off, 64));
            float sum = 0.f;
#pragma unroll
            for (int tj = 0; tj < 4; ++tj) {
                float p = __expf(s[ti][tj][r] - mv);
                s[ti][tj][r] = p;
                sum += p;
            }
#pragma unroll
            for (int off = 1; off < 16; off <<= 1) sum += __shfl_xor(sum, off, 64);
            inv_l[ti][r] = 1.0f / sum;
        }

    // P: C-layout -> LDS (A-layout rows, chunk-swizzled)
    bfu16* P = &P_s[wid][0];
#pragma unroll
    for (int ti = 0; ti < 4; ++ti)
#pragma unroll
        for (int tj = 0; tj < 4; ++tj)
#pragma unroll
            for (int r = 0; r < 4; ++r) {
                int i = ti * 16 + quad * 4 + r;
                int j = tj * 16 + l16;
                P[i * 64 + (((j >> 3) ^ VSWZ(i)) * 8) + (j & 7)] = f2b(s[ti][tj][r]);
            }
    __syncthreads();

    // O = P @ V : K-dim = 64 -> 2 k-steps
    f32x4 oacc[4][2];
#pragma unroll
    for (int i = 0; i < 4; ++i) { oacc[i][0] = zero; oacc[i][1] = zero; }
#pragma unroll
    for (int ks = 0; ks < 2; ++ks) {
        short8 pa[4], vb[2];
#pragma unroll
        for (int mt = 0; mt < 4; ++mt) {
            int rm = mt * 16 + l16;
            pa[mt] = *(const short8*)(P + rm * 64 + (((ks * 4 + quad) ^ VSWZ(rm)) * 8));
        }
#pragma unroll
        for (int nt = 0; nt < 2; ++nt) {
            int rv = nt * 16 + l16;
            vb[nt] = *(const short8*)(&Vt_s[wid][rv * 64 + (((ks * 4 + quad) ^ VSWZ(rv)) * 8)]);
        }
#pragma unroll
        for (int mt = 0; mt < 4; ++mt)
#pragma unroll
            for (int nt = 0; nt < 2; ++nt)
                oacc[mt][nt] = __builtin_amdgcn_mfma_f32_16x16x32_bf16(pa[mt], vb[nt], oacc[mt][nt], 0, 0, 0);
    }

    // write O (window-reverse scatter), normalize by 1/l
#pragma unroll
    for (int mt = 0; mt < 4; ++mt)
#pragma unroll
        for (int nt = 0; nt < 2; ++nt)
#pragma unroll
            for (int r = 0; r < 4; ++r) {
                int i = mt * 16 + quad * 4 + r;
                int col = head * 32 + nt * 16 + l16;
                o[(size_t)ROWOF(i) * 384 + col] = f2b(oacc[mt][nt][r] * inv_l[mt][r]);
            }
#undef ROWOF
}

// ---------------- launch ----------------
extern "C" void kernel_launch(void* const* d_in, const int* in_sizes, int n_in,
                              void* d_out, int out_size, void* d_ws, size_t ws_size,
                              hipStream_t stream) {
    const float* x      = (const float*)d_in[0];
    const float* n1g    = (const float*)d_in[1];
    const float* n1b    = (const float*)d_in[2];
    const float* qkv_w  = (const float*)d_in[3];
    const float* qkv_b  = (const float*)d_in[4];
    const float* proj_w = (const float*)d_in[5];
    const float* proj_b = (const float*)d_in[6];
    const float* rpb    = (const float*)d_in[7];
    const float* n2g    = (const float*)d_in[8];
    const float* n2b    = (const float*)d_in[9];
    const float* fc1_w  = (const float*)d_in[10];
    const float* fc1_b  = (const float*)d_in[11];
    const float* fc2_w  = (const float*)d_in[12];
    const float* fc2_b  = (const float*)d_in[13];
    float* out = (float*)d_out;

    char* ws = (char*)d_ws;
    size_t off = 0;
    auto alloc = [&](size_t bytes) { void* p = ws + off; off = (off + bytes + 255) & ~(size_t)255; return p; };
    bfu16* WqT = (bfu16*)alloc(442368ull * 2);       // [1152][384]
    bfu16* WpT = (bfu16*)alloc(147456ull * 2);       // [384][384]
    bfu16* W1T = (bfu16*)alloc(589824ull * 2);       // [1536][384]
    bfu16* W2T = (bfu16*)alloc(589824ull * 2);       // [384][1536]
    bfu16* act = (bfu16*)alloc(50331648ull * 2);     // h / o / h2  [131072][384]
    bfu16* big = (bfu16*)alloc(201326592ull * 2);    // qkv [131072][1152] then hid [131072][1536]
    float* x1  = (float*)alloc(50331648ull * 4);     // residual mid [131072][384]

    const int M = 131072;

    k_convw<<<dim3((442368 + 255) / 256), 256, 0, stream>>>(qkv_w, WqT, 384, 1152);
    k_convw<<<dim3((147456 + 255) / 256), 256, 0, stream>>>(proj_w, WpT, 384, 384);
    k_convw<<<dim3((589824 + 255) / 256), 256, 0, stream>>>(fc1_w, W1T, 384, 1536);
    k_convw<<<dim3((589824 + 255) / 256), 256, 0, stream>>>(fc2_w, W2T, 1536, 384);

    k_ln<<<dim3(M / 4), 256, 0, stream>>>(x, n1g, n1b, act);

    k_gemm<0><<<dim3(1152 / 128, M / 128), 256, 0, stream>>>(act, WqT, qkv_b, nullptr, nullptr, big, 1152, 384);

    k_attn<<<dim3(6144), 256, 0, stream>>>(big, rpb, act);

    k_gemm<1><<<dim3(384 / 128, M / 128), 256, 0, stream>>>(act, WpT, proj_b, x, x1, nullptr, 384, 384);

    k_ln<<<dim3(M / 4), 256, 0, stream>>>(x1, n2g, n2b, act);

    k_gemm<2><<<dim3(1536 / 128, M / 128), 256, 0, stream>>>(act, W1T, fc1_b, nullptr, nullptr, big, 1536, 384);

    k_gemm<1><<<dim3(384 / 128, M / 128), 256, 0, stream>>>(big, W2T, fc2_b, x1, out, nullptr, 384, 1536);
}

// Round 3
// 1520.971 us; speedup vs baseline: 1.0761x; 1.0172x over previous
//
#include <hip/hip_runtime.h>

typedef __attribute__((ext_vector_type(4))) float f32x4;
typedef __attribute__((ext_vector_type(8))) short short8;
typedef unsigned short bfu16;

typedef const __attribute__((address_space(1))) void* as1cv;
typedef __attribute__((address_space(3))) void* as3v;
#define GLL16(gp, lp) __builtin_amdgcn_global_load_lds((as1cv)(const void*)(gp), (as3v)(void*)(lp), 16, 0, 0)

__device__ __forceinline__ bfu16 f2b(float f) {
    union { float f; unsigned u; } x; x.f = f;
    unsigned r = x.u + 0x7fffu + ((x.u >> 16) & 1u);
    return (bfu16)(r >> 16);
}

// fast erf-based gelu: Abramowitz-Stegun 7.1.26, |err(erf)| <= 1.5e-7, single path (no divergence)
__device__ __forceinline__ float fast_gelu(float v) {
    float z = v * 0.70710678118654752f;
    float a = fabsf(z);
    float t = __builtin_amdgcn_rcpf(fmaf(0.3275911f, a, 1.0f));
    float poly = t * fmaf(t, fmaf(t, fmaf(t, fmaf(t, 1.061405429f, -1.453152027f), 1.421413741f), -0.284496736f), 0.254829592f);
    float e = __expf(-a * a);
    float erfa = fmaf(-poly, e, 1.0f);       // erf(|z|), >= 0
    float erfz = copysignf(erfa, z);
    return 0.5f * v * (1.0f + erfz);
}

// row-swizzle for 128B-stride LDS rows (8 x 16B chunks): chunk ^= ((row ^ (row>>3)) & 7)
#define VSWZ(d) ((((d) ^ ((d) >> 3)) & 7))

// ---------------- weight convert + transpose: W[K][N] fp32 -> Wt[N][K] bf16 ----------------
__global__ __launch_bounds__(256) void k_convw(const float* __restrict__ W, bfu16* __restrict__ Wt,
                                               int K, int N) {
    int idx = blockIdx.x * 256 + threadIdx.x;
    if (idx >= K * N) return;
    int k = idx / N, n = idx - k * N;
    Wt[(size_t)n * K + k] = f2b(W[idx]);
}

// ---------------- LayerNorm over C=384, one wave per row, bf16 out ----------------
__global__ __launch_bounds__(256) void k_ln(const float* __restrict__ x, const float* __restrict__ g,
                                            const float* __restrict__ b, bfu16* __restrict__ y) {
    int wid = threadIdx.x >> 6, lane = threadIdx.x & 63;
    size_t row = (size_t)blockIdx.x * 4 + wid;
    const float* xr = x + row * 384;
    float v[6];
#pragma unroll
    for (int i = 0; i < 6; ++i) v[i] = xr[lane + i * 64];
    float s = 0.f;
#pragma unroll
    for (int i = 0; i < 6; ++i) s += v[i];
#pragma unroll
    for (int off = 1; off < 64; off <<= 1) s += __shfl_xor(s, off, 64);
    float mean = s * (1.0f / 384.0f);
    float q = 0.f;
#pragma unroll
    for (int i = 0; i < 6; ++i) { float d = v[i] - mean; q += d * d; }
#pragma unroll
    for (int off = 1; off < 64; off <<= 1) q += __shfl_xor(q, off, 64);
    float inv = rsqrtf(q * (1.0f / 384.0f) + 1e-5f);
    bfu16* yr = y + row * 384;
#pragma unroll
    for (int i = 0; i < 6; ++i) {
        int c = lane + i * 64;
        yr[c] = f2b((v[i] - mean) * inv * g[c] + b[c]);
    }
}

// ---------------- GEMM: C[M][N] = A[M][K](bf16) @ Bt[N][K]^T(bf16) + bias, fused epilogue ----
// EPI 0: out bf16         1: out fp32 = acc+bias+res (res stride == N)     2: out bf16 = gelu(acc+bias)
// LDS tiles [128][32] bf16, chunk-XOR swizzled (round 0; conflicts measured 0).
// Double-buffered 2-phase pipeline: each iteration = barrier -> STAGE(next buf) -> COMPUTE(cur buf).
// The vmcnt(0) drain emitted by the barrier lands AFTER a full tile of ds_read+MFMA, so the
// global_load_lds latency hides under compute instead of being serially exposed per K-step.
// Race-safety: buffer b written at iter t+1 was last read at iter t-1... separated by the iter-t
// barrier; buffer read at iter t was staged at iter t-1, drained by the iter-t barrier.
template <int EPI>
__global__ __launch_bounds__(256) void k_gemm(const bfu16* __restrict__ A, const bfu16* __restrict__ Bt,
                                              const float* __restrict__ bias, const float* __restrict__ res,
                                              float* __restrict__ outf, bfu16* __restrict__ outb,
                                              int N, int K) {
    __shared__ __align__(16) bfu16 As[2][128 * 32];
    __shared__ __align__(16) bfu16 Bs[2][128 * 32];
    const int tid = threadIdx.x, wid = tid >> 6, lane = tid & 63;
    const int quad = lane >> 4, l16 = lane & 15;
    const int m0 = blockIdx.y * 128, n0 = blockIdx.x * 128;
    const int wm = (wid >> 1) * 64, wn = (wid & 1) * 64;
    // staging: lane l stages (local row l>>2, k-chunk (l&3)^((l>>3)&3)) -> LDS is chunk-swizzled
    const int srow = lane >> 2;
    const int skc = (lane & 3) ^ ((lane >> 3) & 3);
    const bfu16* Ag = A + (size_t)(m0 + wid * 32 + srow) * K + skc * 8;
    const bfu16* Bg = Bt + (size_t)(n0 + wid * 32 + srow) * K + skc * 8;
    const int lofs0 = (wid * 32) * 32;
    const int lofs1 = (wid * 32 + 16) * 32;
    // read-side swizzled chunk offset (constant per lane: row bits 1-2 == l16 bits 1-2)
    const int swq = (quad ^ ((l16 >> 1) & 3)) * 8;

    const f32x4 zero = {0.f, 0.f, 0.f, 0.f};
    f32x4 acc[4][4];
#pragma unroll
    for (int i = 0; i < 4; ++i)
#pragma unroll
        for (int j = 0; j < 4; ++j) acc[i][j] = zero;

#define STAGE(buf, k0)                                \
    do {                                              \
        GLL16(Ag + (k0), &As[buf][lofs0]);            \
        GLL16(Ag + (k0) + 16 * K, &As[buf][lofs1]);   \
        GLL16(Bg + (k0), &Bs[buf][lofs0]);            \
        GLL16(Bg + (k0) + 16 * K, &Bs[buf][lofs1]);   \
    } while (0)

    const int nk = K >> 5;
    STAGE(0, 0);
    for (int t = 0; t < nk; ++t) {
        __syncthreads();                           // drains prev STAGE (vmcnt 0) + guards buf reuse
        if (t + 1 < nk) STAGE((t + 1) & 1, (t + 1) * 32);
        const int buf = t & 1;
        short8 af[4], bfr[4];
#pragma unroll
        for (int u = 0; u < 4; ++u) af[u]  = *(const short8*)(&As[buf][(wm + u * 16 + l16) * 32 + swq]);
#pragma unroll
        for (int u = 0; u < 4; ++u) bfr[u] = *(const short8*)(&Bs[buf][(wn + u * 16 + l16) * 32 + swq]);
#pragma unroll
        for (int mt = 0; mt < 4; ++mt)
#pragma unroll
            for (int nt = 0; nt < 4; ++nt)
                acc[mt][nt] = __builtin_amdgcn_mfma_f32_16x16x32_bf16(af[mt], bfr[nt], acc[mt][nt], 0, 0, 0);
    }
#undef STAGE

    // hoist the 4 distinct bias values out of the 64-iteration store loop
    float bv[4];
#pragma unroll
    for (int nt = 0; nt < 4; ++nt) bv[nt] = bias[n0 + wn + nt * 16 + l16];

#pragma unroll
    for (int mt = 0; mt < 4; ++mt)
#pragma unroll
        for (int nt = 0; nt < 4; ++nt)
#pragma unroll
            for (int r = 0; r < 4; ++r) {
                int m = m0 + wm + mt * 16 + quad * 4 + r;
                int n = n0 + wn + nt * 16 + l16;
                float v = acc[mt][nt][r] + bv[nt];
                size_t off = (size_t)m * N + n;
                if (EPI == 0) {
                    outb[off] = f2b(v);
                } else if (EPI == 1) {
                    outf[off] = v + res[off];
                } else {
                    outb[off] = f2b(fast_gelu(v));
                }
            }
}

// ---------------- windowed attention: one wave per (window, head) ----------------
// qkv: [131072][1152] bf16 (natural row order); o: [131072][384] bf16 (natural row order)
// P_s / Vt_s rows are 128B (bank-aligned stride) -> 16-way read conflicts unswizzled;
// chunk-XOR with VSWZ(row) spreads the 8 chunk-spans -> 2 lanes/bank (free).
__global__ __launch_bounds__(256) void k_attn(const bfu16* __restrict__ qkv, const float* __restrict__ rpb,
                                              bfu16* __restrict__ o) {
    __shared__ __align__(16) bfu16 P_s[4][64 * 64];
    __shared__ __align__(16) bfu16 Vt_s[4][32 * 64];
    const int wid = threadIdx.x >> 6, lane = threadIdx.x & 63;
    const int quad = lane >> 4, l16 = lane & 15;
    const int gid = blockIdx.x * 4 + wid;          // 0..24575
    const int win = gid / 12, head = gid - win * 12;
    const int b = win >> 6, wi = (win >> 3) & 7, wj = win & 7;
    const int rowbase = b * 4096 + wi * 8 * 64 + wj * 8;
#define ROWOF(t) (rowbase + ((t) >> 3) * 64 + ((t) & 7))

    // stage V transposed (swizzled): Vt[d][j], lane owns token j=lane
    {
        const bfu16* vr = qkv + (size_t)ROWOF(lane) * 1152 + 768 + head * 32;
        short8 v0 = *(const short8*)(vr);
        short8 v1 = *(const short8*)(vr + 8);
        short8 v2 = *(const short8*)(vr + 16);
        short8 v3 = *(const short8*)(vr + 24);
        bfu16* vt = &Vt_s[wid][0];
        const int lh = lane >> 3, ll = lane & 7;
#pragma unroll
        for (int j = 0; j < 8; ++j) {
            vt[(0  + j) * 64 + ((lh ^ VSWZ(0  + j)) * 8) + ll] = (bfu16)v0[j];
            vt[(8  + j) * 64 + ((lh ^ VSWZ(8  + j)) * 8) + ll] = (bfu16)v1[j];
            vt[(16 + j) * 64 + ((lh ^ VSWZ(16 + j)) * 8) + ll] = (bfu16)v2[j];
            vt[(24 + j) * 64 + ((lh ^ VSWZ(24 + j)) * 8) + ll] = (bfu16)v3[j];
        }
    }

    // Q/K fragments straight from global (both K-major): A[m=lane&15][k=quad*8+j]
    short8 qf[4], kf[4];
#pragma unroll
    for (int t = 0; t < 4; ++t) {
        const size_t r = (size_t)ROWOF(t * 16 + l16) * 1152;
        qf[t] = *(const short8*)(qkv + r + head * 32 + quad * 8);
        kf[t] = *(const short8*)(qkv + r + 384 + head * 32 + quad * 8);
    }
    const f32x4 zero = {0.f, 0.f, 0.f, 0.f};
    f32x4 s[4][4];
#pragma unroll
    for (int ti = 0; ti < 4; ++ti)
#pragma unroll
        for (int tj = 0; tj < 4; ++tj)
            s[ti][tj] = __builtin_amdgcn_mfma_f32_16x16x32_bf16(qf[ti], kf[tj], zero, 0, 0, 0);

    // softmax over j (rows i = ti*16 + quad*4 + r live in 16-lane groups)
    const float scale = 0.17677669529663689f;  // 1/sqrt(32)
    float inv_l[4][4];
#pragma unroll
    for (int ti = 0; ti < 4; ++ti)
#pragma unroll
        for (int r = 0; r < 4; ++r) {
            int i = ti * 16 + quad * 4 + r;
            int yi = i >> 3, xi = i & 7;
            float mv = -1e30f;
#pragma unroll
            for (int tj = 0; tj < 4; ++tj) {
                int j = tj * 16 + l16;
                int idx = (yi - (j >> 3) + 7) * 15 + (xi - (j & 7) + 7);
                float sv = s[ti][tj][r] * scale + rpb[idx * 12 + head];
                s[ti][tj][r] = sv;
                mv = fmaxf(mv, sv);
            }
#pragma unroll
            for (int off = 1; off < 16; off <<= 1) mv = fmaxf(mv, __shfl_xor(mv, off, 64));
            float sum = 0.f;
#pragma unroll
            for (int tj = 0; tj < 4; ++tj) {
                float p = __expf(s[ti][tj][r] - mv);
                s[ti][tj][r] = p;
                sum += p;
            }
#pragma unroll
            for (int off = 1; off < 16; off <<= 1) sum += __shfl_xor(sum, off, 64);
            inv_l[ti][r] = 1.0f / sum;
        }

    // P: C-layout -> LDS (A-layout rows, chunk-swizzled)
    bfu16* P = &P_s[wid][0];
#pragma unroll
    for (int ti = 0; ti < 4; ++ti)
#pragma unroll
        for (int tj = 0; tj < 4; ++tj)
#pragma unroll
            for (int r = 0; r < 4; ++r) {
                int i = ti * 16 + quad * 4 + r;
                int j = tj * 16 + l16;
                P[i * 64 + (((j >> 3) ^ VSWZ(i)) * 8) + (j & 7)] = f2b(s[ti][tj][r]);
            }
    __syncthreads();

    // O = P @ V : K-dim = 64 -> 2 k-steps
    f32x4 oacc[4][2];
#pragma unroll
    for (int i = 0; i < 4; ++i) { oacc[i][0] = zero; oacc[i][1] = zero; }
#pragma unroll
    for (int ks = 0; ks < 2; ++ks) {
        short8 pa[4], vb[2];
#pragma unroll
        for (int mt = 0; mt < 4; ++mt) {
            int rm = mt * 16 + l16;
            pa[mt] = *(const short8*)(P + rm * 64 + (((ks * 4 + quad) ^ VSWZ(rm)) * 8));
        }
#pragma unroll
        for (int nt = 0; nt < 2; ++nt) {
            int rv = nt * 16 + l16;
            vb[nt] = *(const short8*)(&Vt_s[wid][rv * 64 + (((ks * 4 + quad) ^ VSWZ(rv)) * 8)]);
        }
#pragma unroll
        for (int mt = 0; mt < 4; ++mt)
#pragma unroll
            for (int nt = 0; nt < 2; ++nt)
                oacc[mt][nt] = __builtin_amdgcn_mfma_f32_16x16x32_bf16(pa[mt], vb[nt], oacc[mt][nt], 0, 0, 0);
    }

    // write O (window-reverse scatter), normalize by 1/l
#pragma unroll
    for (int mt = 0; mt < 4; ++mt)
#pragma unroll
        for (int nt = 0; nt < 2; ++nt)
#pragma unroll
            for (int r = 0; r < 4; ++r) {
                int i = mt * 16 + quad * 4 + r;
                int col = head * 32 + nt * 16 + l16;
                o[(size_t)ROWOF(i) * 384 + col] = f2b(oacc[mt][nt][r] * inv_l[mt][r]);
            }
#undef ROWOF
}

// ---------------- launch ----------------
extern "C" void kernel_launch(void* const* d_in, const int* in_sizes, int n_in,
                              void* d_out, int out_size, void* d_ws, size_t ws_size,
                              hipStream_t stream) {
    const float* x      = (const float*)d_in[0];
    const float* n1g    = (const float*)d_in[1];
    const float* n1b    = (const float*)d_in[2];
    const float* qkv_w  = (const float*)d_in[3];
    const float* qkv_b  = (const float*)d_in[4];
    const float* proj_w = (const float*)d_in[5];
    const float* proj_b = (const float*)d_in[6];
    const float* rpb    = (const float*)d_in[7];
    const float* n2g    = (const float*)d_in[8];
    const float* n2b    = (const float*)d_in[9];
    const float* fc1_w  = (const float*)d_in[10];
    const float* fc1_b  = (const float*)d_in[11];
    const float* fc2_w  = (const float*)d_in[12];
    const float* fc2_b  = (const float*)d_in[13];
    float* out = (float*)d_out;

    char* ws = (char*)d_ws;
    size_t off = 0;
    auto alloc = [&](size_t bytes) { void* p = ws + off; off = (off + bytes + 255) & ~(size_t)255; return p; };
    bfu16* WqT = (bfu16*)alloc(442368ull * 2);       // [1152][384]
    bfu16* WpT = (bfu16*)alloc(147456ull * 2);       // [384][384]
    bfu16* W1T = (bfu16*)alloc(589824ull * 2);       // [1536][384]
    bfu16* W2T = (bfu16*)alloc(589824ull * 2);       // [384][1536]
    bfu16* act = (bfu16*)alloc(50331648ull * 2);     // h / o / h2  [131072][384]
    bfu16* big = (bfu16*)alloc(201326592ull * 2);    // qkv [131072][1152] then hid [131072][1536]
    float* x1  = (float*)alloc(50331648ull * 4);     // residual mid [131072][384]

    const int M = 131072;

    k_convw<<<dim3((442368 + 255) / 256), 256, 0, stream>>>(qkv_w, WqT, 384, 1152);
    k_convw<<<dim3((147456 + 255) / 256), 256, 0, stream>>>(proj_w, WpT, 384, 384);
    k_convw<<<dim3((589824 + 255) / 256), 256, 0, stream>>>(fc1_w, W1T, 384, 1536);
    k_convw<<<dim3((589824 + 255) / 256), 256, 0, stream>>>(fc2_w, W2T, 1536, 384);

    k_ln<<<dim3(M / 4), 256, 0, stream>>>(x, n1g, n1b, act);

    k_gemm<0><<<dim3(1152 / 128, M / 128), 256, 0, stream>>>(act, WqT, qkv_b, nullptr, nullptr, big, 1152, 384);

    k_attn<<<dim3(6144), 256, 0, stream>>>(big, rpb, act);

    k_gemm<1><<<dim3(384 / 128, M / 128), 256, 0, stream>>>(act, WpT, proj_b, x, x1, nullptr, 384, 384);

    k_ln<<<dim3(M / 4), 256, 0, stream>>>(x1, n2g, n2b, act);

    k_gemm<2><<<dim3(1536 / 128, M / 128), 256, 0, stream>>>(act, W1T, fc1_b, nullptr, nullptr, big, 1536, 384);

    k_gemm<1><<<dim3(384 / 128, M / 128), 256, 0, stream>>>(big, W2T, fc2_b, x1, out, nullptr, 384, 1536);
}

// Round 5
// 1505.455 us; speedup vs baseline: 1.0872x; 1.0103x over previous
//
#include <hip/hip_runtime.h>

typedef __attribute__((ext_vector_type(4))) float f32x4;
typedef __attribute__((ext_vector_type(8))) short short8;
typedef unsigned short bfu16;

typedef const __attribute__((address_space(1))) void* as1cv;
typedef __attribute__((address_space(3))) void* as3v;
#define GLL16(gp, lp) __builtin_amdgcn_global_load_lds((as1cv)(const void*)(gp), (as3v)(void*)(lp), 16, 0, 0)

__device__ __forceinline__ bfu16 f2b(float f) {
    union { float f; unsigned u; } x; x.f = f;
    unsigned r = x.u + 0x7fffu + ((x.u >> 16) & 1u);
    return (bfu16)(r >> 16);
}

// fast erf-based gelu: Abramowitz-Stegun 7.1.26, |err(erf)| <= 1.5e-7, single path (no divergence)
__device__ __forceinline__ float fast_gelu(float v) {
    float z = v * 0.70710678118654752f;
    float a = fabsf(z);
    float t = __builtin_amdgcn_rcpf(fmaf(0.3275911f, a, 1.0f));
    float poly = t * fmaf(t, fmaf(t, fmaf(t, fmaf(t, 1.061405429f, -1.453152027f), 1.421413741f), -0.284496736f), 0.254829592f);
    float e = __expf(-a * a);
    float erfa = fmaf(-poly, e, 1.0f);       // erf(|z|), >= 0
    float erfz = copysignf(erfa, z);
    return 0.5f * v * (1.0f + erfz);
}

// row-swizzle for 128B-stride LDS rows (8 x 16B chunks): chunk ^= ((row ^ (row>>3)) & 7)
#define VSWZ(d) ((((d) ^ ((d) >> 3)) & 7))

// ---------------- weight convert + transpose: W[K][N] fp32 -> Wt[N][K] bf16 ----------------
__global__ __launch_bounds__(256) void k_convw(const float* __restrict__ W, bfu16* __restrict__ Wt,
                                               int K, int N) {
    int idx = blockIdx.x * 256 + threadIdx.x;
    if (idx >= K * N) return;
    int k = idx / N, n = idx - k * N;
    Wt[(size_t)n * K + k] = f2b(W[idx]);
}

// ---------------- LayerNorm over C=384, one wave per row, bf16 out ----------------
__global__ __launch_bounds__(256) void k_ln(const float* __restrict__ x, const float* __restrict__ g,
                                            const float* __restrict__ b, bfu16* __restrict__ y) {
    int wid = threadIdx.x >> 6, lane = threadIdx.x & 63;
    size_t row = (size_t)blockIdx.x * 4 + wid;
    const float* xr = x + row * 384;
    float v[6];
#pragma unroll
    for (int i = 0; i < 6; ++i) v[i] = xr[lane + i * 64];
    float s = 0.f;
#pragma unroll
    for (int i = 0; i < 6; ++i) s += v[i];
#pragma unroll
    for (int off = 1; off < 64; off <<= 1) s += __shfl_xor(s, off, 64);
    float mean = s * (1.0f / 384.0f);
    float q = 0.f;
#pragma unroll
    for (int i = 0; i < 6; ++i) { float d = v[i] - mean; q += d * d; }
#pragma unroll
    for (int off = 1; off < 64; off <<= 1) q += __shfl_xor(q, off, 64);
    float inv = rsqrtf(q * (1.0f / 384.0f) + 1e-5f);
    bfu16* yr = y + row * 384;
#pragma unroll
    for (int i = 0; i < 6; ++i) {
        int c = lane + i * 64;
        yr[c] = f2b((v[i] - mean) * inv * g[c] + b[c]);
    }
}

// ---------------- GEMM: C[M][N] = A[M][K](bf16) @ Bt[N][K]^T(bf16) + bias, fused epilogue ----
// EPI 0: out bf16         1: out fp32 = acc+bias+res (res stride == N)     2: out bf16 = gelu(acc+bias)
// LDS tiles [128][32] bf16, chunk-XOR swizzled (round 0; conflicts measured 0).
// Counted-vmcnt pipeline (T3+T4). Depth-2 prefetch; the main-loop wait is
// s_waitcnt vmcnt(4) -- tile t's 4 own loads drained, tile t+1's 4 stay IN FLIGHT across the
// barrier (never vmcnt(0) mid-loop). Invariant: every wave waits its OWN loads before s_barrier
// => after the barrier all waves' tile-t data is in LDS. Second barrier (with lgkmcnt(0) guard:
// own ds_reads complete before passing) protects the buffer from the t+2 overwrite.
// sched_barrier(0) after each raw s_barrier pins LDS-op ordering (guide rule #18).
template <int EPI>
__global__ __launch_bounds__(256) void k_gemm(const bfu16* __restrict__ A, const bfu16* __restrict__ Bt,
                                              const float* __restrict__ bias, const float* __restrict__ res,
                                              float* __restrict__ outf, bfu16* __restrict__ outb,
                                              int N, int K) {
    __shared__ __align__(16) bfu16 As[2][128 * 32];
    __shared__ __align__(16) bfu16 Bs[2][128 * 32];
    const int tid = threadIdx.x, wid = tid >> 6, lane = tid & 63;
    const int quad = lane >> 4, l16 = lane & 15;
    const int m0 = blockIdx.y * 128, n0 = blockIdx.x * 128;
    const int wm = (wid >> 1) * 64, wn = (wid & 1) * 64;
    // staging: lane l stages (local row l>>2, k-chunk (l&3)^((l>>3)&3)) -> LDS is chunk-swizzled
    const int srow = lane >> 2;
    const int skc = (lane & 3) ^ ((lane >> 3) & 3);
    const bfu16* Ag = A + (size_t)(m0 + wid * 32 + srow) * K + skc * 8;
    const bfu16* Bg = Bt + (size_t)(n0 + wid * 32 + srow) * K + skc * 8;
    const int lofs0 = (wid * 32) * 32;
    const int lofs1 = (wid * 32 + 16) * 32;
    // read-side swizzled chunk offset (constant per lane: row bits 1-2 == l16 bits 1-2)
    const int swq = (quad ^ ((l16 >> 1) & 3)) * 8;

    const f32x4 zero = {0.f, 0.f, 0.f, 0.f};
    f32x4 acc[4][4];
#pragma unroll
    for (int i = 0; i < 4; ++i)
#pragma unroll
        for (int j = 0; j < 4; ++j) acc[i][j] = zero;

#define STAGE(buf, k0)                                \
    do {                                              \
        GLL16(Ag + (k0), &As[buf][lofs0]);            \
        GLL16(Ag + (k0) + 16 * K, &As[buf][lofs1]);   \
        GLL16(Bg + (k0), &Bs[buf][lofs0]);            \
        GLL16(Bg + (k0) + 16 * K, &Bs[buf][lofs1]);   \
    } while (0)

    const int nk = K >> 5;   // >= 12 at all call sites
    STAGE(0, 0);
    STAGE(1, 32);
    for (int t = 0; t < nk; ++t) {
        // wait own tile-t loads; keep tile-(t+1)'s 4 loads in flight across the barrier
        if (t < nk - 1) asm volatile("s_waitcnt vmcnt(4)" ::: "memory");
        else            asm volatile("s_waitcnt vmcnt(0)" ::: "memory");
        __builtin_amdgcn_s_barrier();
        __builtin_amdgcn_sched_barrier(0);
        const int buf = t & 1;
        short8 af[4], bfr[4];
#pragma unroll
        for (int u = 0; u < 4; ++u) af[u]  = *(const short8*)(&As[buf][(wm + u * 16 + l16) * 32 + swq]);
#pragma unroll
        for (int u = 0; u < 4; ++u) bfr[u] = *(const short8*)(&Bs[buf][(wn + u * 16 + l16) * 32 + swq]);
#pragma unroll
        for (int mt = 0; mt < 4; ++mt)
#pragma unroll
            for (int nt = 0; nt < 4; ++nt)
                acc[mt][nt] = __builtin_amdgcn_mfma_f32_16x16x32_bf16(af[mt], bfr[nt], acc[mt][nt], 0, 0, 0);
        if (t + 2 < nk) {
            // all waves done READING buf before it is overwritten with tile t+2.
            // lgkmcnt(0): own ds_reads fully complete before passing the barrier.
            asm volatile("s_waitcnt lgkmcnt(0)" ::: "memory");
            __builtin_amdgcn_s_barrier();
            __builtin_amdgcn_sched_barrier(0);
            STAGE(buf, (t + 2) * 32);
        }
    }
#undef STAGE

    // hoist the 4 distinct bias values out of the 64-iteration store loop
    float bv[4];
#pragma unroll
    for (int nt = 0; nt < 4; ++nt) bv[nt] = bias[n0 + wn + nt * 16 + l16];

#pragma unroll
    for (int mt = 0; mt < 4; ++mt)
#pragma unroll
        for (int nt = 0; nt < 4; ++nt)
#pragma unroll
            for (int r = 0; r < 4; ++r) {
                int m = m0 + wm + mt * 16 + quad * 4 + r;
                int n = n0 + wn + nt * 16 + l16;
                float v = acc[mt][nt][r] + bv[nt];
                size_t off = (size_t)m * N + n;
                if (EPI == 0) {
                    outb[off] = f2b(v);
                } else if (EPI == 1) {
                    outf[off] = v + res[off];
                } else {
                    outb[off] = f2b(fast_gelu(v));
                }
            }
}

// ---------------- windowed attention: one wave per (window, head) ----------------
// qkv: [131072][1152] bf16 (natural row order); o: [131072][384] bf16 (natural row order)
// P_s / Vt_s rows are 128B (bank-aligned stride) -> 16-way read conflicts unswizzled;
// chunk-XOR with VSWZ(row) spreads the 8 chunk-spans -> 2 lanes/bank (free).
__global__ __launch_bounds__(256) void k_attn(const bfu16* __restrict__ qkv, const float* __restrict__ rpb,
                                              bfu16* __restrict__ o) {
    __shared__ __align__(16) bfu16 P_s[4][64 * 64];
    __shared__ __align__(16) bfu16 Vt_s[4][32 * 64];
    const int wid = threadIdx.x >> 6, lane = threadIdx.x & 63;
    const int quad = lane >> 4, l16 = lane & 15;
    const int gid = blockIdx.x * 4 + wid;          // 0..24575
    const int win = gid / 12, head = gid - win * 12;
    const int b = win >> 6, wi = (win >> 3) & 7, wj = win & 7;
    const int rowbase = b * 4096 + wi * 8 * 64 + wj * 8;
#define ROWOF(t) (rowbase + ((t) >> 3) * 64 + ((t) & 7))

    // stage V transposed (swizzled): Vt[d][j], lane owns token j=lane
    {
        const bfu16* vr = qkv + (size_t)ROWOF(lane) * 1152 + 768 + head * 32;
        short8 v0 = *(const short8*)(vr);
        short8 v1 = *(const short8*)(vr + 8);
        short8 v2 = *(const short8*)(vr + 16);
        short8 v3 = *(const short8*)(vr + 24);
        bfu16* vt = &Vt_s[wid][0];
        const int lh = lane >> 3, ll = lane & 7;
#pragma unroll
        for (int j = 0; j < 8; ++j) {
            vt[(0  + j) * 64 + ((lh ^ VSWZ(0  + j)) * 8) + ll] = (bfu16)v0[j];
            vt[(8  + j) * 64 + ((lh ^ VSWZ(8  + j)) * 8) + ll] = (bfu16)v1[j];
            vt[(16 + j) * 64 + ((lh ^ VSWZ(16 + j)) * 8) + ll] = (bfu16)v2[j];
            vt[(24 + j) * 64 + ((lh ^ VSWZ(24 + j)) * 8) + ll] = (bfu16)v3[j];
        }
    }

    // Q/K fragments straight from global (both K-major): A[m=lane&15][k=quad*8+j]
    short8 qf[4], kf[4];
#pragma unroll
    for (int t = 0; t < 4; ++t) {
        const size_t r = (size_t)ROWOF(t * 16 + l16) * 1152;
        qf[t] = *(const short8*)(qkv + r + head * 32 + quad * 8);
        kf[t] = *(const short8*)(qkv + r + 384 + head * 32 + quad * 8);
    }
    const f32x4 zero = {0.f, 0.f, 0.f, 0.f};
    f32x4 s[4][4];
#pragma unroll
    for (int ti = 0; ti < 4; ++ti)
#pragma unroll
        for (int tj = 0; tj < 4; ++tj)
            s[ti][tj] = __builtin_amdgcn_mfma_f32_16x16x32_bf16(qf[ti], kf[tj], zero, 0, 0, 0);

    // softmax over j (rows i = ti*16 + quad*4 + r live in 16-lane groups)
    const float scale = 0.17677669529663689f;  // 1/sqrt(32)
    float inv_l[4][4];
#pragma unroll
    for (int ti = 0; ti < 4; ++ti)
#pragma unroll
        for (int r = 0; r < 4; ++r) {
            int i = ti * 16 + quad * 4 + r;
            int yi = i >> 3, xi = i & 7;
            float mv = -1e30f;
#pragma unroll
            for (int tj = 0; tj < 4; ++tj) {
                int j = tj * 16 + l16;
                int idx = (yi - (j >> 3) + 7) * 15 + (xi - (j & 7) + 7);
                float sv = s[ti][tj][r] * scale + rpb[idx * 12 + head];
                s[ti][tj][r] = sv;
                mv = fmaxf(mv, sv);
            }
#pragma unroll
            for (int off = 1; off < 16; off <<= 1) mv = fmaxf(mv, __shfl_xor(mv, off, 64));
            float sum = 0.f;
#pragma unroll
            for (int tj = 0; tj < 4; ++tj) {
                float p = __expf(s[ti][tj][r] - mv);
                s[ti][tj][r] = p;
                sum += p;
            }
#pragma unroll
            for (int off = 1; off < 16; off <<= 1) sum += __shfl_xor(sum, off, 64);
            inv_l[ti][r] = 1.0f / sum;
        }

    // P: C-layout -> LDS (A-layout rows, chunk-swizzled)
    bfu16* P = &P_s[wid][0];
#pragma unroll
    for (int ti = 0; ti < 4; ++ti)
#pragma unroll
        for (int tj = 0; tj < 4; ++tj)
#pragma unroll
            for (int r = 0; r < 4; ++r) {
                int i = ti * 16 + quad * 4 + r;
                int j = tj * 16 + l16;
                P[i * 64 + (((j >> 3) ^ VSWZ(i)) * 8) + (j & 7)] = f2b(s[ti][tj][r]);
            }
    __syncthreads();

    // O = P @ V : K-dim = 64 -> 2 k-steps
    f32x4 oacc[4][2];
#pragma unroll
    for (int i = 0; i < 4; ++i) { oacc[i][0] = zero; oacc[i][1] = zero; }
#pragma unroll
    for (int ks = 0; ks < 2; ++ks) {
        short8 pa[4], vb[2];
#pragma unroll
        for (int mt = 0; mt < 4; ++mt) {
            int rm = mt * 16 + l16;
            pa[mt] = *(const short8*)(P + rm * 64 + (((ks * 4 + quad) ^ VSWZ(rm)) * 8));
        }
#pragma unroll
        for (int nt = 0; nt < 2; ++nt) {
            int rv = nt * 16 + l16;
            vb[nt] = *(const short8*)(&Vt_s[wid][rv * 64 + (((ks * 4 + quad) ^ VSWZ(rv)) * 8)]);
        }
#pragma unroll
        for (int mt = 0; mt < 4; ++mt)
#pragma unroll
            for (int nt = 0; nt < 2; ++nt)
                oacc[mt][nt] = __builtin_amdgcn_mfma_f32_16x16x32_bf16(pa[mt], vb[nt], oacc[mt][nt], 0, 0, 0);
    }

    // write O (window-reverse scatter), normalize by 1/l
#pragma unroll
    for (int mt = 0; mt < 4; ++mt)
#pragma unroll
        for (int nt = 0; nt < 2; ++nt)
#pragma unroll
            for (int r = 0; r < 4; ++r) {
                int i = mt * 16 + quad * 4 + r;
                int col = head * 32 + nt * 16 + l16;
                o[(size_t)ROWOF(i) * 384 + col] = f2b(oacc[mt][nt][r] * inv_l[mt][r]);
            }
#undef ROWOF
}

// ---------------- launch ----------------
extern "C" void kernel_launch(void* const* d_in, const int* in_sizes, int n_in,
                              void* d_out, int out_size, void* d_ws, size_t ws_size,
                              hipStream_t stream) {
    const float* x      = (const float*)d_in[0];
    const float* n1g    = (const float*)d_in[1];
    const float* n1b    = (const float*)d_in[2];
    const float* qkv_w  = (const float*)d_in[3];
    const float* qkv_b  = (const float*)d_in[4];
    const float* proj_w = (const float*)d_in[5];
    const float* proj_b = (const float*)d_in[6];
    const float* rpb    = (const float*)d_in[7];
    const float* n2g    = (const float*)d_in[8];
    const float* n2b    = (const float*)d_in[9];
    const float* fc1_w  = (const float*)d_in[10];
    const float* fc1_b  = (const float*)d_in[11];
    const float* fc2_w  = (const float*)d_in[12];
    const float* fc2_b  = (const float*)d_in[13];
    float* out = (float*)d_out;

    char* ws = (char*)d_ws;
    size_t off = 0;
    auto alloc = [&](size_t bytes) { void* p = ws + off; off = (off + bytes + 255) & ~(size_t)255; return p; };
    bfu16* WqT = (bfu16*)alloc(442368ull * 2);       // [1152][384]
    bfu16* WpT = (bfu16*)alloc(147456ull * 2);       // [384][384]
    bfu16* W1T = (bfu16*)alloc(589824ull * 2);       // [1536][384]
    bfu16* W2T = (bfu16*)alloc(589824ull * 2);       // [384][1536]
    bfu16* act = (bfu16*)alloc(50331648ull * 2);     // h / o / h2  [131072][384]
    bfu16* big = (bfu16*)alloc(201326592ull * 2);    // qkv [131072][1152] then hid [131072][1536]
    float* x1  = (float*)alloc(50331648ull * 4);     // residual mid [131072][384]

    const int M = 131072;

    k_convw<<<dim3((442368 + 255) / 256), 256, 0, stream>>>(qkv_w, WqT, 384, 1152);
    k_convw<<<dim3((147456 + 255) / 256), 256, 0, stream>>>(proj_w, WpT, 384, 384);
    k_convw<<<dim3((589824 + 255) / 256), 256, 0, stream>>>(fc1_w, W1T, 384, 1536);
    k_convw<<<dim3((589824 + 255) / 256), 256, 0, stream>>>(fc2_w, W2T, 1536, 384);

    k_ln<<<dim3(M / 4), 256, 0, stream>>>(x, n1g, n1b, act);

    k_gemm<0><<<dim3(1152 / 128, M / 128), 256, 0, stream>>>(act, WqT, qkv_b, nullptr, nullptr, big, 1152, 384);

    k_attn<<<dim3(6144), 256, 0, stream>>>(big, rpb, act);

    k_gemm<1><<<dim3(384 / 128, M / 128), 256, 0, stream>>>(act, WpT, proj_b, x, x1, nullptr, 384, 384);

    k_ln<<<dim3(M / 4), 256, 0, stream>>>(x1, n2g, n2b, act);

    k_gemm<2><<<dim3(1536 / 128, M / 128), 256, 0, stream>>>(act, W1T, fc1_b, nullptr, nullptr, big, 1536, 384);

    k_gemm<1><<<dim3(384 / 128, M / 128), 256, 0, stream>>>(big, W2T, fc2_b, x1, out, nullptr, 384, 1536);
}

// Round 6
// 1470.397 us; speedup vs baseline: 1.1131x; 1.0238x over previous
//
#include <hip/hip_runtime.h>

typedef __attribute__((ext_vector_type(4))) float f32x4;
typedef __attribute__((ext_vector_type(8))) short short8;
typedef unsigned short bfu16;

typedef const __attribute__((address_space(1))) void* as1cv;
typedef __attribute__((address_space(3))) void* as3v;
#define GLL16(gp, lp) __builtin_amdgcn_global_load_lds((as1cv)(const void*)(gp), (as3v)(void*)(lp), 16, 0, 0)

__device__ __forceinline__ bfu16 f2b(float f) {
    union { float f; unsigned u; } x; x.f = f;
    unsigned r = x.u + 0x7fffu + ((x.u >> 16) & 1u);
    return (bfu16)(r >> 16);
}

// fast erf-based gelu: Abramowitz-Stegun 7.1.26, |err(erf)| <= 1.5e-7, single path (no divergence)
__device__ __forceinline__ float fast_gelu(float v) {
    float z = v * 0.70710678118654752f;
    float a = fabsf(z);
    float t = __builtin_amdgcn_rcpf(fmaf(0.3275911f, a, 1.0f));
    float poly = t * fmaf(t, fmaf(t, fmaf(t, fmaf(t, 1.061405429f, -1.453152027f), 1.421413741f), -0.284496736f), 0.254829592f);
    float e = __expf(-a * a);
    float erfa = fmaf(-poly, e, 1.0f);       // erf(|z|), >= 0
    float erfz = copysignf(erfa, z);
    return 0.5f * v * (1.0f + erfz);
}

// row-swizzle for 128B-stride LDS rows (8 x 16B chunks): chunk ^= ((row ^ (row>>3)) & 7)
#define VSWZ(d) ((((d) ^ ((d) >> 3)) & 7))

// ---------------- weight convert + transpose: W[K][N] fp32 -> Wt[N][K] bf16 ----------------
__global__ __launch_bounds__(256) void k_convw(const float* __restrict__ W, bfu16* __restrict__ Wt,
                                               int K, int N) {
    int idx = blockIdx.x * 256 + threadIdx.x;
    if (idx >= K * N) return;
    int k = idx / N, n = idx - k * N;
    Wt[(size_t)n * K + k] = f2b(W[idx]);
}

// ---------------- LayerNorm over C=384, one wave per row, bf16 out ----------------
__global__ __launch_bounds__(256) void k_ln(const float* __restrict__ x, const float* __restrict__ g,
                                            const float* __restrict__ b, bfu16* __restrict__ y) {
    int wid = threadIdx.x >> 6, lane = threadIdx.x & 63;
    size_t row = (size_t)blockIdx.x * 4 + wid;
    const float* xr = x + row * 384;
    float v[6];
#pragma unroll
    for (int i = 0; i < 6; ++i) v[i] = xr[lane + i * 64];
    float s = 0.f;
#pragma unroll
    for (int i = 0; i < 6; ++i) s += v[i];
#pragma unroll
    for (int off = 1; off < 64; off <<= 1) s += __shfl_xor(s, off, 64);
    float mean = s * (1.0f / 384.0f);
    float q = 0.f;
#pragma unroll
    for (int i = 0; i < 6; ++i) { float d = v[i] - mean; q += d * d; }
#pragma unroll
    for (int off = 1; off < 64; off <<= 1) q += __shfl_xor(q, off, 64);
    float inv = rsqrtf(q * (1.0f / 384.0f) + 1e-5f);
    bfu16* yr = y + row * 384;
#pragma unroll
    for (int i = 0; i < 6; ++i) {
        int c = lane + i * 64;
        yr[c] = f2b((v[i] - mean) * inv * g[c] + b[c]);
    }
}

// ---------------- GEMM: C[M][N] = A[M][K](bf16) @ Bt[N][K]^T(bf16) + bias, fused epilogue ----
// EPI 0: out bf16         1: out fp32 = acc+bias+res (res stride == N)     2: out bf16 = gelu(acc+bias)
// LDS tiles [128][32] bf16, chunk-XOR swizzled (conflicts measured 0).
// Counted-vmcnt depth-2 pipeline (rounds 3/5; +2%).
// Round 5: XCD-aware block remap (T1). HW round-robins consecutive dispatch IDs over 8 XCDs, so
// the gridDim.x n-blocks sharing one A-panel land on different XCD L2s -> panel re-fetched from
// HBM up to gridDim.x times. Bijective remap new=(orig&7)*(nwg/8)+(orig>>3) gives each XCD a
// contiguous band of new-ids with n varying fastest -> panel-sharing blocks are adjacent-in-time
// on ONE XCD; A-panels become L2-resident (qkv: 9x reuse, fc1: 12x, fc2/proj: 3x).
template <int EPI>
__global__ __launch_bounds__(256) void k_gemm(const bfu16* __restrict__ A, const bfu16* __restrict__ Bt,
                                              const float* __restrict__ bias, const float* __restrict__ res,
                                              float* __restrict__ outf, bfu16* __restrict__ outb,
                                              int N, int K) {
    __shared__ __align__(16) bfu16 As[2][128 * 32];
    __shared__ __align__(16) bfu16 Bs[2][128 * 32];
    const int tid = threadIdx.x, wid = tid >> 6, lane = tid & 63;
    const int quad = lane >> 4, l16 = lane & 15;
    // XCD-aware bijective remap (identity if grid not divisible by 8)
    const int nbx = gridDim.x;
    const int nwg = nbx * gridDim.y;
    int orig = blockIdx.y * nbx + blockIdx.x;          // HW dispatch index (x fastest)
    int id = ((nwg & 7) == 0) ? ((orig & 7) * (nwg >> 3) + (orig >> 3)) : orig;
    const int m0 = (id / nbx) * 128, n0 = (id % nbx) * 128;
    const int wm = (wid >> 1) * 64, wn = (wid & 1) * 64;
    // staging: lane l stages (local row l>>2, k-chunk (l&3)^((l>>3)&3)) -> LDS is chunk-swizzled
    const int srow = lane >> 2;
    const int skc = (lane & 3) ^ ((lane >> 3) & 3);
    const bfu16* Ag = A + (size_t)(m0 + wid * 32 + srow) * K + skc * 8;
    const bfu16* Bg = Bt + (size_t)(n0 + wid * 32 + srow) * K + skc * 8;
    const int lofs0 = (wid * 32) * 32;
    const int lofs1 = (wid * 32 + 16) * 32;
    // read-side swizzled chunk offset (constant per lane: row bits 1-2 == l16 bits 1-2)
    const int swq = (quad ^ ((l16 >> 1) & 3)) * 8;

    const f32x4 zero = {0.f, 0.f, 0.f, 0.f};
    f32x4 acc[4][4];
#pragma unroll
    for (int i = 0; i < 4; ++i)
#pragma unroll
        for (int j = 0; j < 4; ++j) acc[i][j] = zero;

#define STAGE(buf, k0)                                \
    do {                                              \
        GLL16(Ag + (k0), &As[buf][lofs0]);            \
        GLL16(Ag + (k0) + 16 * K, &As[buf][lofs1]);   \
        GLL16(Bg + (k0), &Bs[buf][lofs0]);            \
        GLL16(Bg + (k0) + 16 * K, &Bs[buf][lofs1]);   \
    } while (0)

    const int nk = K >> 5;   // >= 12 at all call sites
    STAGE(0, 0);
    STAGE(1, 32);
    for (int t = 0; t < nk; ++t) {
        // wait own tile-t loads; keep tile-(t+1)'s 4 loads in flight across the barrier
        if (t < nk - 1) asm volatile("s_waitcnt vmcnt(4)" ::: "memory");
        else            asm volatile("s_waitcnt vmcnt(0)" ::: "memory");
        __builtin_amdgcn_s_barrier();
        __builtin_amdgcn_sched_barrier(0);
        const int buf = t & 1;
        short8 af[4], bfr[4];
#pragma unroll
        for (int u = 0; u < 4; ++u) af[u]  = *(const short8*)(&As[buf][(wm + u * 16 + l16) * 32 + swq]);
#pragma unroll
        for (int u = 0; u < 4; ++u) bfr[u] = *(const short8*)(&Bs[buf][(wn + u * 16 + l16) * 32 + swq]);
#pragma unroll
        for (int mt = 0; mt < 4; ++mt)
#pragma unroll
            for (int nt = 0; nt < 4; ++nt)
                acc[mt][nt] = __builtin_amdgcn_mfma_f32_16x16x32_bf16(af[mt], bfr[nt], acc[mt][nt], 0, 0, 0);
        if (t + 2 < nk) {
            // all waves done READING buf before it is overwritten with tile t+2.
            asm volatile("s_waitcnt lgkmcnt(0)" ::: "memory");
            __builtin_amdgcn_s_barrier();
            __builtin_amdgcn_sched_barrier(0);
            STAGE(buf, (t + 2) * 32);
        }
    }
#undef STAGE

    // hoist the 4 distinct bias values out of the 64-iteration store loop
    float bv[4];
#pragma unroll
    for (int nt = 0; nt < 4; ++nt) bv[nt] = bias[n0 + wn + nt * 16 + l16];

#pragma unroll
    for (int mt = 0; mt < 4; ++mt)
#pragma unroll
        for (int nt = 0; nt < 4; ++nt)
#pragma unroll
            for (int r = 0; r < 4; ++r) {
                int m = m0 + wm + mt * 16 + quad * 4 + r;
                int n = n0 + wn + nt * 16 + l16;
                float v = acc[mt][nt][r] + bv[nt];
                size_t off = (size_t)m * N + n;
                if (EPI == 0) {
                    outb[off] = f2b(v);
                } else if (EPI == 1) {
                    outf[off] = v + res[off];
                } else {
                    outb[off] = f2b(fast_gelu(v));
                }
            }
}

// ---------------- windowed attention: one wave per (window, head) ----------------
// qkv: [131072][1152] bf16 (natural row order); o: [131072][384] bf16 (natural row order)
// P_s / Vt_s chunk-XOR swizzled (conflicts 0). XCD remap: the 3 consecutive blocks covering one
// window's 12 heads read the SAME 147KB of qkv rows -> keep them on one XCD L2.
__global__ __launch_bounds__(256) void k_attn(const bfu16* __restrict__ qkv, const float* __restrict__ rpb,
                                              bfu16* __restrict__ o) {
    __shared__ __align__(16) bfu16 P_s[4][64 * 64];
    __shared__ __align__(16) bfu16 Vt_s[4][32 * 64];
    const int wid = threadIdx.x >> 6, lane = threadIdx.x & 63;
    const int quad = lane >> 4, l16 = lane & 15;
    const int nbk = gridDim.x;
    int orig = blockIdx.x;
    int bid = ((nbk & 7) == 0) ? ((orig & 7) * (nbk >> 3) + (orig >> 3)) : orig;
    const int gid = bid * 4 + wid;                 // 0..24575
    const int win = gid / 12, head = gid - win * 12;
    const int b = win >> 6, wi = (win >> 3) & 7, wj = win & 7;
    const int rowbase = b * 4096 + wi * 8 * 64 + wj * 8;
#define ROWOF(t) (rowbase + ((t) >> 3) * 64 + ((t) & 7))

    // stage V transposed (swizzled): Vt[d][j], lane owns token j=lane
    {
        const bfu16* vr = qkv + (size_t)ROWOF(lane) * 1152 + 768 + head * 32;
        short8 v0 = *(const short8*)(vr);
        short8 v1 = *(const short8*)(vr + 8);
        short8 v2 = *(const short8*)(vr + 16);
        short8 v3 = *(const short8*)(vr + 24);
        bfu16* vt = &Vt_s[wid][0];
        const int lh = lane >> 3, ll = lane & 7;
#pragma unroll
        for (int j = 0; j < 8; ++j) {
            vt[(0  + j) * 64 + ((lh ^ VSWZ(0  + j)) * 8) + ll] = (bfu16)v0[j];
            vt[(8  + j) * 64 + ((lh ^ VSWZ(8  + j)) * 8) + ll] = (bfu16)v1[j];
            vt[(16 + j) * 64 + ((lh ^ VSWZ(16 + j)) * 8) + ll] = (bfu16)v2[j];
            vt[(24 + j) * 64 + ((lh ^ VSWZ(24 + j)) * 8) + ll] = (bfu16)v3[j];
        }
    }

    // Q/K fragments straight from global (both K-major): A[m=lane&15][k=quad*8+j]
    short8 qf[4], kf[4];
#pragma unroll
    for (int t = 0; t < 4; ++t) {
        const size_t r = (size_t)ROWOF(t * 16 + l16) * 1152;
        qf[t] = *(const short8*)(qkv + r + head * 32 + quad * 8);
        kf[t] = *(const short8*)(qkv + r + 384 + head * 32 + quad * 8);
    }
    const f32x4 zero = {0.f, 0.f, 0.f, 0.f};
    f32x4 s[4][4];
#pragma unroll
    for (int ti = 0; ti < 4; ++ti)
#pragma unroll
        for (int tj = 0; tj < 4; ++tj)
            s[ti][tj] = __builtin_amdgcn_mfma_f32_16x16x32_bf16(qf[ti], kf[tj], zero, 0, 0, 0);

    // softmax over j (rows i = ti*16 + quad*4 + r live in 16-lane groups)
    const float scale = 0.17677669529663689f;  // 1/sqrt(32)
    float inv_l[4][4];
#pragma unroll
    for (int ti = 0; ti < 4; ++ti)
#pragma unroll
        for (int r = 0; r < 4; ++r) {
            int i = ti * 16 + quad * 4 + r;
            int yi = i >> 3, xi = i & 7;
            float mv = -1e30f;
#pragma unroll
            for (int tj = 0; tj < 4; ++tj) {
                int j = tj * 16 + l16;
                int idx = (yi - (j >> 3) + 7) * 15 + (xi - (j & 7) + 7);
                float sv = s[ti][tj][r] * scale + rpb[idx * 12 + head];
                s[ti][tj][r] = sv;
                mv = fmaxf(mv, sv);
            }
#pragma unroll
            for (int off = 1; off < 16; off <<= 1) mv = fmaxf(mv, __shfl_xor(mv, off, 64));
            float sum = 0.f;
#pragma unroll
            for (int tj = 0; tj < 4; ++tj) {
                float p = __expf(s[ti][tj][r] - mv);
                s[ti][tj][r] = p;
                sum += p;
            }
#pragma unroll
            for (int off = 1; off < 16; off <<= 1) sum += __shfl_xor(sum, off, 64);
            inv_l[ti][r] = 1.0f / sum;
        }

    // P: C-layout -> LDS (A-layout rows, chunk-swizzled)
    bfu16* P = &P_s[wid][0];
#pragma unroll
    for (int ti = 0; ti < 4; ++ti)
#pragma unroll
        for (int tj = 0; tj < 4; ++tj)
#pragma unroll
            for (int r = 0; r < 4; ++r) {
                int i = ti * 16 + quad * 4 + r;
                int j = tj * 16 + l16;
                P[i * 64 + (((j >> 3) ^ VSWZ(i)) * 8) + (j & 7)] = f2b(s[ti][tj][r]);
            }
    __syncthreads();

    // O = P @ V : K-dim = 64 -> 2 k-steps
    f32x4 oacc[4][2];
#pragma unroll
    for (int i = 0; i < 4; ++i) { oacc[i][0] = zero; oacc[i][1] = zero; }
#pragma unroll
    for (int ks = 0; ks < 2; ++ks) {
        short8 pa[4], vb[2];
#pragma unroll
        for (int mt = 0; mt < 4; ++mt) {
            int rm = mt * 16 + l16;
            pa[mt] = *(const short8*)(P + rm * 64 + (((ks * 4 + quad) ^ VSWZ(rm)) * 8));
        }
#pragma unroll
        for (int nt = 0; nt < 2; ++nt) {
            int rv = nt * 16 + l16;
            vb[nt] = *(const short8*)(&Vt_s[wid][rv * 64 + (((ks * 4 + quad) ^ VSWZ(rv)) * 8)]);
        }
#pragma unroll
        for (int mt = 0; mt < 4; ++mt)
#pragma unroll
            for (int nt = 0; nt < 2; ++nt)
                oacc[mt][nt] = __builtin_amdgcn_mfma_f32_16x16x32_bf16(pa[mt], vb[nt], oacc[mt][nt], 0, 0, 0);
    }

    // write O (window-reverse scatter), normalize by 1/l
#pragma unroll
    for (int mt = 0; mt < 4; ++mt)
#pragma unroll
        for (int nt = 0; nt < 2; ++nt)
#pragma unroll
            for (int r = 0; r < 4; ++r) {
                int i = mt * 16 + quad * 4 + r;
                int col = head * 32 + nt * 16 + l16;
                o[(size_t)ROWOF(i) * 384 + col] = f2b(oacc[mt][nt][r] * inv_l[mt][r]);
            }
#undef ROWOF
}

// ---------------- launch ----------------
extern "C" void kernel_launch(void* const* d_in, const int* in_sizes, int n_in,
                              void* d_out, int out_size, void* d_ws, size_t ws_size,
                              hipStream_t stream) {
    const float* x      = (const float*)d_in[0];
    const float* n1g    = (const float*)d_in[1];
    const float* n1b    = (const float*)d_in[2];
    const float* qkv_w  = (const float*)d_in[3];
    const float* qkv_b  = (const float*)d_in[4];
    const float* proj_w = (const float*)d_in[5];
    const float* proj_b = (const float*)d_in[6];
    const float* rpb    = (const float*)d_in[7];
    const float* n2g    = (const float*)d_in[8];
    const float* n2b    = (const float*)d_in[9];
    const float* fc1_w  = (const float*)d_in[10];
    const float* fc1_b  = (const float*)d_in[11];
    const float* fc2_w  = (const float*)d_in[12];
    const float* fc2_b  = (const float*)d_in[13];
    float* out = (float*)d_out;

    char* ws = (char*)d_ws;
    size_t off = 0;
    auto alloc = [&](size_t bytes) { void* p = ws + off; off = (off + bytes + 255) & ~(size_t)255; return p; };
    bfu16* WqT = (bfu16*)alloc(442368ull * 2);       // [1152][384]
    bfu16* WpT = (bfu16*)alloc(147456ull * 2);       // [384][384]
    bfu16* W1T = (bfu16*)alloc(589824ull * 2);       // [1536][384]
    bfu16* W2T = (bfu16*)alloc(589824ull * 2);       // [384][1536]
    bfu16* act = (bfu16*)alloc(50331648ull * 2);     // h / o / h2  [131072][384]
    bfu16* big = (bfu16*)alloc(201326592ull * 2);    // qkv [131072][1152] then hid [131072][1536]
    float* x1  = (float*)alloc(50331648ull * 4);     // residual mid [131072][384]

    const int M = 131072;

    k_convw<<<dim3((442368 + 255) / 256), 256, 0, stream>>>(qkv_w, WqT, 384, 1152);
    k_convw<<<dim3((147456 + 255) / 256), 256, 0, stream>>>(proj_w, WpT, 384, 384);
    k_convw<<<dim3((589824 + 255) / 256), 256, 0, stream>>>(fc1_w, W1T, 384, 1536);
    k_convw<<<dim3((589824 + 255) / 256), 256, 0, stream>>>(fc2_w, W2T, 1536, 384);

    k_ln<<<dim3(M / 4), 256, 0, stream>>>(x, n1g, n1b, act);

    k_gemm<0><<<dim3(1152 / 128, M / 128), 256, 0, stream>>>(act, WqT, qkv_b, nullptr, nullptr, big, 1152, 384);

    k_attn<<<dim3(6144), 256, 0, stream>>>(big, rpb, act);

    k_gemm<1><<<dim3(384 / 128, M / 128), 256, 0, stream>>>(act, WpT, proj_b, x, x1, nullptr, 384, 384);

    k_ln<<<dim3(M / 4), 256, 0, stream>>>(x1, n2g, n2b, act);

    k_gemm<2><<<dim3(1536 / 128, M / 128), 256, 0, stream>>>(act, W1T, fc1_b, nullptr, nullptr, big, 1536, 384);

    k_gemm<1><<<dim3(384 / 128, M / 128), 256, 0, stream>>>(big, W2T, fc2_b, x1, out, nullptr, 384, 1536);
}